// Round 8
// baseline (254.231 us; speedup 1.0000x reference)
//
#include <hip/hip_runtime.h>

#define NSAMP 2048
#define DIM 1024
#define NCLS 224
#define PERCLS 224
#define CH 16
#define KSL 128                    // k per k-group; block spans 2*KSL = 256 k
#define NSLICE 4
#define TOPBLKS ((NSAMP / CH) * NSLICE)   // 512
#define BOTBLKS (NCLS * NSLICE)           // 896

struct Ws {
  int cls[NSAMP];
  int within[NSAMP];
  int order[NSAMP];
  int offsets[NCLS + 1];
  int pad_[3];                      // 16B-align the partial arrays
  float top_part[NSLICE][NSAMP][NCLS];
  float bot_part[NSLICE][NSAMP][PERCLS];
};

// ---------------- prep: cls/within + class-grouped sample order ----------------
__global__ __launch_bounds__(256) void prep_kernel(const int* __restrict__ target,
                                                   Ws* __restrict__ ws) {
  __shared__ int cnt[NCLS];
  __shared__ int cur[NCLS];
  __shared__ int sc[256];
  int tid = threadIdx.x;
  for (int c = tid; c < NCLS; c += 256) cnt[c] = 0;
  __syncthreads();
  for (int n = tid; n < NSAMP; n += 256) {
    int t = target[n];
    int c = t / PERCLS;
    ws->cls[n] = c;
    ws->within[n] = t - c * PERCLS;
    atomicAdd(&cnt[c], 1);
  }
  __syncthreads();
  int v = (tid < NCLS) ? cnt[tid] : 0;
  sc[tid] = v;
  __syncthreads();
  for (int off = 1; off < 256; off <<= 1) {
    int a = (tid >= off) ? sc[tid - off] : 0;
    __syncthreads();
    sc[tid] += a;
    __syncthreads();
  }
  if (tid < NCLS) {
    int excl = sc[tid] - cnt[tid];
    ws->offsets[tid] = excl;
    cur[tid] = excl;
  }
  if (tid == 0) ws->offsets[NCLS] = NSAMP;
  __syncthreads();
  for (int n = tid; n < NSAMP; n += 256) {
    int c = ws->cls[n];
    int pos = atomicAdd(&cur[c], 1);
    ws->order[pos] = n;
  }
}

// ---------------- partial: 8 samples x 4 cols per thread, depth-3 prefetch ----
// waves: (kg, sg); lanes 0..55 = col-group (4 cols each). Group = 4 k rows:
// 4 coalesced float4 weight loads + 8 broadcast b128 x reads + 128 FMAs.
// 32 groups cover KSL=128 k. Depth-3 rotation: consume group g, then issue
// loads for group g+3 (~2 COMPUTE phases of latency cover).
__global__ __launch_bounds__(256) void partial_kernel(const float* __restrict__ x,
                                                      const float* __restrict__ tw,
                                                      const float* __restrict__ bw,
                                                      Ws* __restrict__ ws) {
  __shared__ float xs[2][CH][KSL];   // 16 KB; reused as merge buffer
  const int tid = threadIdx.x;
  const int lane = tid & 63;
  const int wave = tid >> 6;
  const int kg = wave >> 1;          // k-group 0/1 (wave-uniform)
  const int sg = wave & 1;           // sample-group: samples sg*8..sg*8+7
  const int bid = blockIdx.x;

  const bool is_top = bid < TOPBLKS;
  int n0 = 0, c = 0, bs, start = 0, K = CH;
  if (is_top) {
    bs = bid & 3;
    n0 = (bid >> 2) * CH;
  } else {
    int b = bid - TOPBLKS;
    bs = b & 3;
    c = b >> 2;
    start = ws->offsets[c];
    K = ws->offsets[c + 1] - start;
    if (K == 0) return;
  }
  const int kbase = bs * (2 * KSL) + kg * KSL;
  const float* Wbase = is_top ? (tw + (size_t)kbase * NCLS)
                              : (bw + (size_t)c * (DIM * PERCLS) + (size_t)kbase * PERCLS);
  const float4* W4 = (const float4*)Wbase + lane;          // cols [lane*4, lane*4+4)
  const float4* xb = (const float4*)xs + kg * 512 + sg * 256;  // [sample][32 float4]
  float4* red4 = (float4*)xs;                               // merge view [16][56]

#define FMA4(A, XQ, W0, W1, W2, W3)                                   \
  A.x = fmaf(XQ.x, W0.x, A.x); A.y = fmaf(XQ.x, W0.y, A.y);           \
  A.z = fmaf(XQ.x, W0.z, A.z); A.w = fmaf(XQ.x, W0.w, A.w);           \
  A.x = fmaf(XQ.y, W1.x, A.x); A.y = fmaf(XQ.y, W1.y, A.y);           \
  A.z = fmaf(XQ.y, W1.z, A.z); A.w = fmaf(XQ.y, W1.w, A.w);           \
  A.x = fmaf(XQ.z, W2.x, A.x); A.y = fmaf(XQ.z, W2.y, A.y);           \
  A.z = fmaf(XQ.z, W2.z, A.z); A.w = fmaf(XQ.z, W2.w, A.w);           \
  A.x = fmaf(XQ.w, W3.x, A.x); A.y = fmaf(XQ.w, W3.y, A.y);           \
  A.z = fmaf(XQ.w, W3.z, A.z); A.w = fmaf(XQ.w, W3.w, A.w)

#define COMPUTE(W0, W1, W2, W3, G)                                    \
  { _Pragma("unroll")                                                 \
    for (int s = 0; s < 8; ++s) {                                     \
      float4 xq = xb[s * 32 + (G)];                                   \
      FMA4(acc[s], xq, W0, W1, W2, W3);                               \
    } }

#define LOADW(B0, B1, B2, B3)                                         \
  B0 = Wp[0]; B1 = Wp[56]; B2 = Wp[112]; B3 = Wp[168]; Wp += 224;

// one 3-group round at base group G: consume a,b,c; refill each for G+3..G+5
#define ROUND3(G)                                                     \
  COMPUTE(a0, a1, a2, a3, (G))     LOADW(a0, a1, a2, a3)              \
  COMPUTE(b0, b1, b2, b3, (G) + 1) LOADW(b0, b1, b2, b3)              \
  COMPUTE(c0, c1, c2, c3, (G) + 2) LOADW(c0, c1, c2, c3)

  for (int chunk = 0; chunk < K; chunk += CH) {
    const int S = min(CH, K - chunk);
    __syncthreads();   // xs free (stage target / previous merge reads done)

    // stage x: 1024 float4 (16 KB), 4 per thread, coalesced
#pragma unroll
    for (int pass = 0; pass < 4; ++pass) {
      int i = tid + pass * 256;
      int kgx = i >> 9;
      int ss = (i >> 5) & 15;
      int q = i & 31;
      int n;
      if (is_top) n = n0 + ss;
      else        n = ws->order[start + min(chunk + ss, K - 1)];
      ((float4*)xs)[i] =
          *(const float4*)(x + (size_t)n * DIM + bs * (2 * KSL) + kgx * KSL + q * 4);
    }
    __syncthreads();

    float4 acc[8];
#pragma unroll
    for (int s = 0; s < 8; ++s) acc[s] = make_float4(0.f, 0.f, 0.f, 0.f);

    if (lane < 56) {
      const float4* Wp = W4;
      float4 a0, a1, a2, a3, b0, b1, b2, b3, c0, c1, c2, c3;
      LOADW(a0, a1, a2, a3)   // group 0
      LOADW(b0, b1, b2, b3)   // group 1
      LOADW(c0, c1, c2, c3)   // group 2
      ROUND3(0)  ROUND3(3)  ROUND3(6)  ROUND3(9)
      ROUND3(12) ROUND3(15) ROUND3(18) ROUND3(21)
      ROUND3(24)                               // groups 0..26 consumed; loads thru 29
      COMPUTE(a0, a1, a2, a3, 27) LOADW(a0, a1, a2, a3)   // load group 30
      COMPUTE(b0, b1, b2, b3, 28) LOADW(b0, b1, b2, b3)   // load group 31
      COMPUTE(c0, c1, c2, c3, 29)
      COMPUTE(a0, a1, a2, a3, 30)
      COMPUTE(b0, b1, b2, b3, 31)
    }

    // merge kg=1 into kg=0 via LDS (reuse xs), then write out
    __syncthreads();   // all xs compute reads done
    if (kg == 1 && lane < 56) {
#pragma unroll
      for (int s = 0; s < 8; ++s) red4[(sg * 8 + s) * 56 + lane] = acc[s];
    }
    __syncthreads();
    if (kg == 0 && lane < 56) {
      if (is_top) {
#pragma unroll
        for (int s = 0; s < 8; ++s) {
          float4 o = red4[(sg * 8 + s) * 56 + lane];
          acc[s].x += o.x; acc[s].y += o.y; acc[s].z += o.z; acc[s].w += o.w;
          *(float4*)&ws->top_part[bs][n0 + sg * 8 + s][lane * 4] = acc[s];
        }
      } else {
#pragma unroll
        for (int s = 0; s < 8; ++s) {
          int sl = sg * 8 + s;
          if (sl < S) {
            float4 o = red4[sl * 56 + lane];
            acc[s].x += o.x; acc[s].y += o.y; acc[s].z += o.z; acc[s].w += o.w;
            int n = ws->order[start + chunk + sl];
            *(float4*)&ws->bot_part[bs][n][lane * 4] = acc[s];
          }
        }
      }
    }
  }
#undef ROUND3
#undef LOADW
#undef COMPUTE
#undef FMA4
}

// ---------------- final: reduce partials + both softmaxes + product -----------
__global__ __launch_bounds__(256) void final_kernel(const float* __restrict__ tb,
                                                    const float* __restrict__ bb,
                                                    const Ws* __restrict__ ws,
                                                    float* __restrict__ out) {
  __shared__ float lt[8][NCLS];
  __shared__ float lb[8][NCLS];
  const int tid = threadIdx.x;
  const int n0 = blockIdx.x * 8;
  const int p = tid;

  if (p < NCLS) {
    float tbias = tb[p];
#pragma unroll
    for (int s = 0; s < 8; ++s) {
      int n = n0 + s;
      int c = ws->cls[n];
      float t = tbias;
      float b = bb[(size_t)c * PERCLS + p];
#pragma unroll
      for (int dc = 0; dc < NSLICE; ++dc) t += ws->top_part[dc][n][p];
#pragma unroll
      for (int dc = 0; dc < NSLICE; ++dc) b += ws->bot_part[dc][n][p];
      lt[s][p] = t;
      lb[s][p] = b;
    }
  }
  __syncthreads();

  const int wv = tid >> 6, lane = tid & 63;
  for (int s = wv * 2; s < wv * 2 + 2; ++s) {
    const int n = n0 + s;
    float v[4], mx = -INFINITY;
#pragma unroll
    for (int j = 0; j < 4; ++j) {
      int pp = lane + 64 * j;
      v[j] = (pp < NCLS) ? lt[s][pp] : -INFINITY;
      mx = fmaxf(mx, v[j]);
    }
#pragma unroll
    for (int m = 32; m >= 1; m >>= 1) mx = fmaxf(mx, __shfl_xor(mx, m));
    float sum = 0.f;
#pragma unroll
    for (int j = 0; j < 4; ++j) {
      int pp = lane + 64 * j;
      if (pp < NCLS) sum += expf(v[j] - mx);
    }
#pragma unroll
    for (int m = 32; m >= 1; m >>= 1) sum += __shfl_xor(sum, m);
    float pt = expf(lt[s][ws->cls[n]] - mx) / sum;

    float mb = -INFINITY;
#pragma unroll
    for (int j = 0; j < 4; ++j) {
      int pp = lane + 64 * j;
      v[j] = (pp < NCLS) ? lb[s][pp] : -INFINITY;
      mb = fmaxf(mb, v[j]);
    }
#pragma unroll
    for (int m = 32; m >= 1; m >>= 1) mb = fmaxf(mb, __shfl_xor(mb, m));
    float sb = 0.f;
#pragma unroll
    for (int j = 0; j < 4; ++j) {
      int pp = lane + 64 * j;
      if (pp < NCLS) sb += expf(v[j] - mb);
    }
#pragma unroll
    for (int m = 32; m >= 1; m >>= 1) sb += __shfl_xor(sb, m);
    float pb = expf(lb[s][ws->within[n]] - mb) / sb;

    if (lane == 0) out[n] = pt * pb;
  }
}

extern "C" void kernel_launch(void* const* d_in, const int* in_sizes, int n_in,
                              void* d_out, int out_size, void* d_ws, size_t ws_size,
                              hipStream_t stream) {
  const float* x  = (const float*)d_in[0];
  const int* tgt  = (const int*)d_in[1];
  const float* tw = (const float*)d_in[2];
  const float* tb = (const float*)d_in[3];
  const float* bw = (const float*)d_in[4];
  const float* bb = (const float*)d_in[5];
  float* out = (float*)d_out;
  Ws* ws = (Ws*)d_ws;

  prep_kernel<<<1, 256, 0, stream>>>(tgt, ws);
  partial_kernel<<<TOPBLKS + BOTBLKS, 256, 0, stream>>>(x, tw, bw, ws);
  final_kernel<<<NSAMP / 8, 256, 0, stream>>>(tb, bb, ws, out);
}

// Round 9
// 131.330 us; speedup vs baseline: 1.9358x; 1.9358x over previous
//
#include <hip/hip_runtime.h>

#define NSAMP 2048
#define DIM 1024
#define NCLS 224
#define PERCLS 224
#define CH 16
#define KSL 256                           // k per slice (block covers full slice)
#define NSLICE 4
#define TOPBLKS ((NSAMP / CH) * NSLICE)   // 512
#define BOTBLKS (NCLS * NSLICE)           // 896
#define NTILE 32                          // 8 k-rows per tile

struct Ws {
  int cls[NSAMP];
  int within[NSAMP];
  int order[NSAMP];
  int offsets[NCLS + 1];
  int pad_[3];
  float top_part[NSLICE][NSAMP][NCLS];
  float bot_part[NSLICE][NSAMP][PERCLS];
};

// ---------------- prep ----------------
__global__ __launch_bounds__(256) void prep_kernel(const int* __restrict__ target,
                                                   Ws* __restrict__ ws) {
  __shared__ int cnt[NCLS];
  __shared__ int cur[NCLS];
  __shared__ int sc[256];
  int tid = threadIdx.x;
  for (int c = tid; c < NCLS; c += 256) cnt[c] = 0;
  __syncthreads();
  for (int n = tid; n < NSAMP; n += 256) {
    int t = target[n];
    int c = t / PERCLS;
    ws->cls[n] = c;
    ws->within[n] = t - c * PERCLS;
    atomicAdd(&cnt[c], 1);
  }
  __syncthreads();
  int v = (tid < NCLS) ? cnt[tid] : 0;
  sc[tid] = v;
  __syncthreads();
  for (int off = 1; off < 256; off <<= 1) {
    int a = (tid >= off) ? sc[tid - off] : 0;
    __syncthreads();
    sc[tid] += a;
    __syncthreads();
  }
  if (tid < NCLS) {
    int excl = sc[tid] - cnt[tid];
    ws->offsets[tid] = excl;
    cur[tid] = excl;
  }
  if (tid == 0) ws->offsets[NCLS] = NSAMP;
  __syncthreads();
  for (int n = tid; n < NSAMP; n += 256) {
    int c = ws->cls[n];
    int pos = atomicAdd(&cur[c], 1);
    ws->order[pos] = n;
  }
}

// ---------------- partial: DMA-pipelined weights through LDS ------------------
// Waves = (sg, ch): 8 samples x 112 cols; lane<56 owns 2 cols (float2).
// Weight slice (256 k x 224 cols, contiguous) = 32 tiles x 8 rows (7168 B).
// 4 LDS tile buffers; depth-3 global_load_lds prefetch; counted vmcnt + raw
// s_barrier per tile (never __syncthreads in the loop: it drains vmcnt(0)).
__global__ __launch_bounds__(256) void partial_kernel(const float* __restrict__ x,
                                                      const float* __restrict__ tw,
                                                      const float* __restrict__ bw,
                                                      Ws* __restrict__ ws) {
  __shared__ float xs[CH][KSL];        // 16 KB
  __shared__ float w_lds[4 * 2048];    // 4 tile buffers x 8 KB = 32 KB
  const int tid = threadIdx.x;
  const int lane = tid & 63;
  const int wave = tid >> 6;
  const int sg = wave >> 1;            // sample half
  const int ch = wave & 1;             // column half
  const int bid = blockIdx.x;

  const bool is_top = bid < TOPBLKS;
  int n0 = 0, c = 0, bs, start = 0, K = CH;
  if (is_top) {
    bs = bid & 3;
    n0 = (bid >> 2) * CH;
  } else {
    int b = bid - TOPBLKS;
    bs = b & 3;
    c = b >> 2;
    start = ws->offsets[c];
    K = ws->offsets[c + 1] - start;
    if (K == 0) return;
  }
  const float* Wslice = is_top ? (tw + (size_t)(bs * KSL) * NCLS)
                               : (bw + (size_t)c * (DIM * PERCLS) + (size_t)(bs * KSL) * PERCLS);
  const int u0 = 2 * wave;             // this wave's stage units (of 8 per tile)
  const int u1s = (2 * wave + 1 < 7) ? (2 * wave + 1) : 6;  // src clamp for pad unit
  const int u1d = 2 * wave + 1;        // dest (unit 7 lands in pad bytes, never read)

  typedef const __attribute__((address_space(1))) unsigned int gu32;
  typedef __attribute__((address_space(3))) unsigned int lu32;

  auto stage_tile = [&](int t) {
    const float* s0 = Wslice + (size_t)t * 1792 + u0 * 256 + lane * 4;
    const float* s1 = Wslice + (size_t)t * 1792 + u1s * 256 + lane * 4;
    float* d0 = &w_lds[(t & 3) * 2048 + u0 * 256];
    float* d1 = &w_lds[(t & 3) * 2048 + u1d * 256];
    __builtin_amdgcn_global_load_lds((gu32*)s0, (lu32*)d0, 16, 0, 0);
    __builtin_amdgcn_global_load_lds((gu32*)s1, (lu32*)d1, 16, 0, 0);
  };

  for (int chunk = 0; chunk < K; chunk += CH) {
    const int S = min(CH, K - chunk);
    __syncthreads();   // xs/w_lds free from previous chunk (queue already drained)

    // stage x: 1024 float4, 4 per thread, coalesced
#pragma unroll
    for (int pass = 0; pass < 4; ++pass) {
      int i = tid + pass * 256;
      int ss = i >> 6;
      int q = i & 63;
      int n;
      if (is_top) n = n0 + ss;
      else        n = ws->order[start + min(chunk + ss, K - 1)];
      ((float4*)xs)[i] = *(const float4*)(x + (size_t)n * DIM + bs * KSL + q * 4);
    }
    __syncthreads();   // drains x loads/writes; vmcnt now 0 -> clean gll counting

    float2 acc[8];
#pragma unroll
    for (int s = 0; s < 8; ++s) acc[s] = make_float2(0.f, 0.f);

    const int co = ch * 112 + lane * 2;

    auto compute_tile = [&](int t) {
      if (lane < 56) {
        const float* wb = &w_lds[(t & 3) * 2048];
#pragma unroll
        for (int g = 0; g < 2; ++g) {
          float2 w0 = *(const float2*)&wb[(g * 4 + 0) * 224 + co];
          float2 w1 = *(const float2*)&wb[(g * 4 + 1) * 224 + co];
          float2 w2 = *(const float2*)&wb[(g * 4 + 2) * 224 + co];
          float2 w3 = *(const float2*)&wb[(g * 4 + 3) * 224 + co];
#pragma unroll
          for (int s = 0; s < 8; ++s) {
            float4 xv = *(const float4*)&xs[sg * 8 + s][t * 8 + g * 4];
            acc[s].x = fmaf(xv.x, w0.x, acc[s].x); acc[s].y = fmaf(xv.x, w0.y, acc[s].y);
            acc[s].x = fmaf(xv.y, w1.x, acc[s].x); acc[s].y = fmaf(xv.y, w1.y, acc[s].y);
            acc[s].x = fmaf(xv.z, w2.x, acc[s].x); acc[s].y = fmaf(xv.z, w2.y, acc[s].y);
            acc[s].x = fmaf(xv.w, w3.x, acc[s].x); acc[s].y = fmaf(xv.w, w3.y, acc[s].y);
          }
        }
      }
    };

    // prologue: tiles 0..2 in flight (6 gll per wave)
    stage_tile(0);
    stage_tile(1);
    stage_tile(2);

    // main: wait own tile-t units (leave 4 = tiles t+1,t+2), sync, prefetch t+3
    for (int t = 0; t < NTILE - 3; ++t) {
      asm volatile("s_waitcnt vmcnt(4)" ::: "memory");
      __builtin_amdgcn_sched_barrier(0);
      __builtin_amdgcn_s_barrier();
      stage_tile(t + 3);
      compute_tile(t);
    }
    asm volatile("s_waitcnt vmcnt(4)" ::: "memory");
    __builtin_amdgcn_sched_barrier(0);
    __builtin_amdgcn_s_barrier();
    compute_tile(NTILE - 3);
    asm volatile("s_waitcnt vmcnt(2)" ::: "memory");
    __builtin_amdgcn_sched_barrier(0);
    __builtin_amdgcn_s_barrier();
    compute_tile(NTILE - 2);
    asm volatile("s_waitcnt vmcnt(0)" ::: "memory");
    __builtin_amdgcn_sched_barrier(0);
    __builtin_amdgcn_s_barrier();
    compute_tile(NTILE - 1);

    // write outputs
    if (lane < 56) {
      if (is_top) {
#pragma unroll
        for (int s = 0; s < 8; ++s)
          *(float2*)&ws->top_part[bs][n0 + sg * 8 + s][co] = acc[s];
      } else {
#pragma unroll
        for (int s = 0; s < 8; ++s) {
          int sl = sg * 8 + s;
          if (sl < S) {
            int n = ws->order[start + chunk + sl];
            *(float2*)&ws->bot_part[bs][n][co] = acc[s];
          }
        }
      }
    }
  }
}

// ---------------- final ----------------
__global__ __launch_bounds__(256) void final_kernel(const float* __restrict__ tb,
                                                    const float* __restrict__ bb,
                                                    const Ws* __restrict__ ws,
                                                    float* __restrict__ out) {
  __shared__ float lt[8][NCLS];
  __shared__ float lb[8][NCLS];
  const int tid = threadIdx.x;
  const int n0 = blockIdx.x * 8;
  const int p = tid;

  if (p < NCLS) {
    float tbias = tb[p];
#pragma unroll
    for (int s = 0; s < 8; ++s) {
      int n = n0 + s;
      int c = ws->cls[n];
      float t = tbias;
      float b = bb[(size_t)c * PERCLS + p];
#pragma unroll
      for (int dc = 0; dc < NSLICE; ++dc) t += ws->top_part[dc][n][p];
#pragma unroll
      for (int dc = 0; dc < NSLICE; ++dc) b += ws->bot_part[dc][n][p];
      lt[s][p] = t;
      lb[s][p] = b;
    }
  }
  __syncthreads();

  const int wv = tid >> 6, lane = tid & 63;
  for (int s = wv * 2; s < wv * 2 + 2; ++s) {
    const int n = n0 + s;
    float v[4], mx = -INFINITY;
#pragma unroll
    for (int j = 0; j < 4; ++j) {
      int pp = lane + 64 * j;
      v[j] = (pp < NCLS) ? lt[s][pp] : -INFINITY;
      mx = fmaxf(mx, v[j]);
    }
#pragma unroll
    for (int m = 32; m >= 1; m >>= 1) mx = fmaxf(mx, __shfl_xor(mx, m));
    float sum = 0.f;
#pragma unroll
    for (int j = 0; j < 4; ++j) {
      int pp = lane + 64 * j;
      if (pp < NCLS) sum += expf(v[j] - mx);
    }
#pragma unroll
    for (int m = 32; m >= 1; m >>= 1) sum += __shfl_xor(sum, m);
    float pt = expf(lt[s][ws->cls[n]] - mx) / sum;

    float mb = -INFINITY;
#pragma unroll
    for (int j = 0; j < 4; ++j) {
      int pp = lane + 64 * j;
      v[j] = (pp < NCLS) ? lb[s][pp] : -INFINITY;
      mb = fmaxf(mb, v[j]);
    }
#pragma unroll
    for (int m = 32; m >= 1; m >>= 1) mb = fmaxf(mb, __shfl_xor(mb, m));
    float sb = 0.f;
#pragma unroll
    for (int j = 0; j < 4; ++j) {
      int pp = lane + 64 * j;
      if (pp < NCLS) sb += expf(v[j] - mb);
    }
#pragma unroll
    for (int m = 32; m >= 1; m >>= 1) sb += __shfl_xor(sb, m);
    float pb = expf(lb[s][ws->within[n]] - mb) / sb;

    if (lane == 0) out[n] = pt * pb;
  }
}

extern "C" void kernel_launch(void* const* d_in, const int* in_sizes, int n_in,
                              void* d_out, int out_size, void* d_ws, size_t ws_size,
                              hipStream_t stream) {
  const float* x  = (const float*)d_in[0];
  const int* tgt  = (const int*)d_in[1];
  const float* tw = (const float*)d_in[2];
  const float* tb = (const float*)d_in[3];
  const float* bw = (const float*)d_in[4];
  const float* bb = (const float*)d_in[5];
  float* out = (float*)d_out;
  Ws* ws = (Ws*)d_ws;

  prep_kernel<<<1, 256, 0, stream>>>(tgt, ws);
  partial_kernel<<<TOPBLKS + BOTBLKS, 256, 0, stream>>>(x, tw, bw, ws);
  final_kernel<<<NSAMP / 8, 256, 0, stream>>>(tb, bb, ws, out);
}

// Round 10
// 97.352 us; speedup vs baseline: 2.6115x; 1.3490x over previous
//
#include <hip/hip_runtime.h>

#define NSAMP 2048
#define DIM 1024
#define NCLS 224
#define PERCLS 224
#define CH 16
#define KSL 256                           // k per slice (block covers full slice)
#define NSLICE 4
#define TOPBLKS ((NSAMP / CH) * NSLICE)   // 512
#define BOTBLKS (NCLS * NSLICE)           // 896

struct Ws {
  int cls[NSAMP];
  int within[NSAMP];
  int order[NSAMP];
  int offsets[NCLS + 1];
  int pad_[3];
  float top_part[NSLICE][NSAMP][NCLS];
  float bot_part[NSLICE][NSAMP][PERCLS];
};

// ---------------- prep ----------------
__global__ __launch_bounds__(256) void prep_kernel(const int* __restrict__ target,
                                                   Ws* __restrict__ ws) {
  __shared__ int cnt[NCLS];
  __shared__ int cur[NCLS];
  __shared__ int sc[256];
  int tid = threadIdx.x;
  for (int c = tid; c < NCLS; c += 256) cnt[c] = 0;
  __syncthreads();
  for (int n = tid; n < NSAMP; n += 256) {
    int t = target[n];
    int c = t / PERCLS;
    ws->cls[n] = c;
    ws->within[n] = t - c * PERCLS;
    atomicAdd(&cnt[c], 1);
  }
  __syncthreads();
  int v = (tid < NCLS) ? cnt[tid] : 0;
  sc[tid] = v;
  __syncthreads();
  for (int off = 1; off < 256; off <<= 1) {
    int a = (tid >= off) ? sc[tid - off] : 0;
    __syncthreads();
    sc[tid] += a;
    __syncthreads();
  }
  if (tid < NCLS) {
    int excl = sc[tid] - cnt[tid];
    ws->offsets[tid] = excl;
    cur[tid] = excl;
  }
  if (tid == 0) ws->offsets[NCLS] = NSAMP;
  __syncthreads();
  for (int n = tid; n < NSAMP; n += 256) {
    int c = ws->cls[n];
    int pos = atomicAdd(&cur[c], 1);
    ws->order[pos] = n;
  }
}

// ---------------- partial: lean 8s x 2c, occupancy-first ----------------------
// 256 thr = 2 sample-halves x 112 col-pairs (cp<112 active; 16 idle/half).
// One (chunk|class) x 256-k slice per block. Weights: coalesced float2 stream,
// ping-pong A/B (4 k-rows each). x: broadcast ds_read_b128 from 16 KB LDS.
// acc 16 + wA 8 + wB 8 + xv 4 + addr ~ <=64 VGPR -> 8 waves/SIMD.
__global__ __launch_bounds__(256) void partial_kernel(const float* __restrict__ x,
                                                      const float* __restrict__ tw,
                                                      const float* __restrict__ bw,
                                                      Ws* __restrict__ ws) {
  __shared__ float xs[CH][KSL];        // 16 KB
  const int tid = threadIdx.x;
  const int sh = tid >> 7;             // sample half: samples sh*8 .. sh*8+7
  const int cp = tid & 127;            // col-pair; active if < 112
  const int bid = blockIdx.x;

  const bool is_top = bid < TOPBLKS;
  int n0 = 0, c = 0, bs, start = 0, K = CH;
  if (is_top) {
    bs = bid & 3;
    n0 = (bid >> 2) * CH;
  } else {
    int b = bid - TOPBLKS;
    bs = b & 3;
    c = b >> 2;
    start = ws->offsets[c];
    K = ws->offsets[c + 1] - start;
    if (K == 0) return;
  }
  const float* Wslice = is_top ? (tw + (size_t)(bs * KSL) * NCLS)
                               : (bw + (size_t)c * (DIM * PERCLS) + (size_t)(bs * KSL) * PERCLS);
  const float2* W2 = (const float2*)Wslice + cp;   // cols (2cp, 2cp+1); k-row stride 112

#define LOADG(R0, R1, R2, R3)                                         \
  R0 = Wp[0]; R1 = Wp[112]; R2 = Wp[224]; R3 = Wp[336]; Wp += 448;

#define COMPUTE(R0, R1, R2, R3, KB)                                   \
  { _Pragma("unroll")                                                 \
    for (int s = 0; s < 8; ++s) {                                     \
      float4 xv = *(const float4*)&xs[sh * 8 + s][(KB)];              \
      acc[s].x = fmaf(xv.x, R0.x, acc[s].x);                          \
      acc[s].y = fmaf(xv.x, R0.y, acc[s].y);                          \
      acc[s].x = fmaf(xv.y, R1.x, acc[s].x);                          \
      acc[s].y = fmaf(xv.y, R1.y, acc[s].y);                          \
      acc[s].x = fmaf(xv.z, R2.x, acc[s].x);                          \
      acc[s].y = fmaf(xv.z, R2.y, acc[s].y);                          \
      acc[s].x = fmaf(xv.w, R3.x, acc[s].x);                          \
      acc[s].y = fmaf(xv.w, R3.y, acc[s].y);                          \
    } }

  for (int chunk = 0; chunk < K; chunk += CH) {
    const int S = min(CH, K - chunk);
    __syncthreads();   // xs free from previous chunk

    // stage x: 1024 float4 (16 KB), 4 per thread, coalesced rows
#pragma unroll
    for (int pass = 0; pass < 4; ++pass) {
      int i = tid + pass * 256;
      int ss = i >> 6;
      int q = i & 63;
      int n;
      if (is_top) n = n0 + ss;
      else        n = ws->order[start + min(chunk + ss, K - 1)];
      ((float4*)xs)[i] = *(const float4*)(x + (size_t)n * DIM + bs * KSL + q * 4);
    }
    __syncthreads();

    float2 acc[8];
#pragma unroll
    for (int s = 0; s < 8; ++s) acc[s] = make_float2(0.f, 0.f);

    if (cp < 112) {
      const float2* Wp = W2;
      float2 A0, A1, A2, A3, B0, B1, B2, B3;
      LOADG(A0, A1, A2, A3)            // k-rows 0..3
      LOADG(B0, B1, B2, B3)            // k-rows 4..7
      // 64 groups of 4 k-rows; pair loop: compute A(2p), B(2p+1), prefetching +2
      for (int p = 0; p < 31; ++p) {
        COMPUTE(A0, A1, A2, A3, 8 * p)
        LOADG(A0, A1, A2, A3)          // group 2p+2
        COMPUTE(B0, B1, B2, B3, 8 * p + 4)
        LOADG(B0, B1, B2, B3)          // group 2p+3
      }
      COMPUTE(A0, A1, A2, A3, 248)     // group 62
      COMPUTE(B0, B1, B2, B3, 252)     // group 63

      // write final partials (no merge needed: thread owns its outputs)
      if (is_top) {
#pragma unroll
        for (int s = 0; s < 8; ++s)
          *(float2*)&ws->top_part[bs][n0 + sh * 8 + s][cp * 2] = acc[s];
      } else {
#pragma unroll
        for (int s = 0; s < 8; ++s) {
          int sl = sh * 8 + s;
          if (sl < S) {
            int n = ws->order[start + chunk + sl];
            *(float2*)&ws->bot_part[bs][n][cp * 2] = acc[s];
          }
        }
      }
    }
  }
#undef LOADG
#undef COMPUTE
}

// ---------------- final ----------------
__global__ __launch_bounds__(256) void final_kernel(const float* __restrict__ tb,
                                                    const float* __restrict__ bb,
                                                    const Ws* __restrict__ ws,
                                                    float* __restrict__ out) {
  __shared__ float lt[8][NCLS];
  __shared__ float lb[8][NCLS];
  const int tid = threadIdx.x;
  const int n0 = blockIdx.x * 8;
  const int p = tid;

  if (p < NCLS) {
    float tbias = tb[p];
#pragma unroll
    for (int s = 0; s < 8; ++s) {
      int n = n0 + s;
      int c = ws->cls[n];
      float t = tbias;
      float b = bb[(size_t)c * PERCLS + p];
#pragma unroll
      for (int dc = 0; dc < NSLICE; ++dc) t += ws->top_part[dc][n][p];
#pragma unroll
      for (int dc = 0; dc < NSLICE; ++dc) b += ws->bot_part[dc][n][p];
      lt[s][p] = t;
      lb[s][p] = b;
    }
  }
  __syncthreads();

  const int wv = tid >> 6, lane = tid & 63;
  for (int s = wv * 2; s < wv * 2 + 2; ++s) {
    const int n = n0 + s;
    float v[4], mx = -INFINITY;
#pragma unroll
    for (int j = 0; j < 4; ++j) {
      int pp = lane + 64 * j;
      v[j] = (pp < NCLS) ? lt[s][pp] : -INFINITY;
      mx = fmaxf(mx, v[j]);
    }
#pragma unroll
    for (int m = 32; m >= 1; m >>= 1) mx = fmaxf(mx, __shfl_xor(mx, m));
    float sum = 0.f;
#pragma unroll
    for (int j = 0; j < 4; ++j) {
      int pp = lane + 64 * j;
      if (pp < NCLS) sum += expf(v[j] - mx);
    }
#pragma unroll
    for (int m = 32; m >= 1; m >>= 1) sum += __shfl_xor(sum, m);
    float pt = expf(lt[s][ws->cls[n]] - mx) / sum;

    float mb = -INFINITY;
#pragma unroll
    for (int j = 0; j < 4; ++j) {
      int pp = lane + 64 * j;
      v[j] = (pp < NCLS) ? lb[s][pp] : -INFINITY;
      mb = fmaxf(mb, v[j]);
    }
#pragma unroll
    for (int m = 32; m >= 1; m >>= 1) mb = fmaxf(mb, __shfl_xor(mb, m));
    float sb = 0.f;
#pragma unroll
    for (int j = 0; j < 4; ++j) {
      int pp = lane + 64 * j;
      if (pp < NCLS) sb += expf(v[j] - mb);
    }
#pragma unroll
    for (int m = 32; m >= 1; m >>= 1) sb += __shfl_xor(sb, m);
    float pb = expf(lb[s][ws->within[n]] - mb) / sb;

    if (lane == 0) out[n] = pt * pb;
  }
}

extern "C" void kernel_launch(void* const* d_in, const int* in_sizes, int n_in,
                              void* d_out, int out_size, void* d_ws, size_t ws_size,
                              hipStream_t stream) {
  const float* x  = (const float*)d_in[0];
  const int* tgt  = (const int*)d_in[1];
  const float* tw = (const float*)d_in[2];
  const float* tb = (const float*)d_in[3];
  const float* bw = (const float*)d_in[4];
  const float* bb = (const float*)d_in[5];
  float* out = (float*)d_out;
  Ws* ws = (Ws*)d_ws;

  prep_kernel<<<1, 256, 0, stream>>>(tgt, ws);
  partial_kernel<<<TOPBLKS + BOTBLKS, 256, 0, stream>>>(x, tw, bw, ws);
  final_kernel<<<NSAMP / 8, 256, 0, stream>>>(tb, bb, ws, out);
}